// Round 3
// baseline (438.074 us; speedup 1.0000x reference)
//
#include <hip/hip_runtime.h>
#include <hip/hip_bf16.h>

typedef __bf16 bf16x8 __attribute__((ext_vector_type(8)));
typedef float f32x4 __attribute__((ext_vector_type(4)));
typedef unsigned short u16;
typedef u16 u16x8 __attribute__((ext_vector_type(8)));
typedef unsigned int u32;
typedef u32 u32x4 __attribute__((ext_vector_type(4)));

#define N_EMBD 1024
#define NH 16
#define HD 64
#define BZ 4
#define TZ 2048
#define QSCALE 0.18033688011f   // 1/sqrt(64) * log2(e)

template<bool B> struct BoolC { static constexpr bool value = B; };

__device__ __forceinline__ u16 f2bf(float f) {
    return __builtin_bit_cast(u16, (__bf16)f);
}

__device__ __forceinline__ void gload16(const void* g, void* l) {
    __builtin_amdgcn_global_load_lds(
        (const __attribute__((address_space(1))) void*)g,
        (__attribute__((address_space(3))) void*)l, 16, 0, 0);
}

// ---------------- fp32 -> bf16 convert (vectorized, optional scale) --------
__global__ void cvt_f32_bf16(const float* __restrict__ src, u16* __restrict__ dst,
                             int n4, float scale) {
    int i = blockIdx.x * blockDim.x + threadIdx.x;
    if (i < n4) {
        float4 f = ((const float4*)src)[i];
        ushort4 o;
        o.x = f2bf(f.x * scale); o.y = f2bf(f.y * scale);
        o.z = f2bf(f.z * scale); o.w = f2bf(f.w * scale);
        ((ushort4*)dst)[i] = o;
    }
}

// ---------------- bf16 GEMM, C = A * B^T + bias ----------------------------
// BM=256, BN=128, BK=64, 512 threads (8 waves = 4 pairs).
// Pair p = waves {2p, 2p+1}: SAME 128x64 output tile, split by K-half:
//   sk = wid&1 selects kh (32-k half) of every 64-k tile -> per wave per phase
//   only 4 A-frag reads (+4 B shared across the 2 m-half phases) for 16 MFMA
//   (m201 read economy, 0.375 reads/MFMA) while keeping perfect CU packing.
// m201 phase shape: ds_read frags; stage 3 gloads; barrier; lgkmcnt(0);
//   setprio(1); 16 MFMA; setprio(0); [vmcnt(6) once per K-tile]; barrier.
// Triple-buffered LDS (144 KiB), tile t stages t+2 -> vmcnt(6) steady state.
// Epilogue: pair K-half reduction via LDS, then sk0 waves store.
// EPI=0: scatter to qkv: Q,K planes [B][H][T][64]; V plane TRANSPOSED [B][H][64][T]
//        (Q plane pre-scaled by QSCALE via Wq/bq scaling)
// EPI=1: plain fp32 [M,1024] with bias b0
template<int EPI>
__global__ __launch_bounds__(512, 2) void gemm_bt(
    const u16* __restrict__ A, const u16* __restrict__ Bm,
    const float* __restrict__ b0, const float* __restrict__ b1, const float* __restrict__ b2,
    void* __restrict__ Cout, int K) {
    __shared__ __align__(16) char SH[147456];
    u16* Ash = (u16*)SH;                 // [3][2][8192]  (buf, kh, 256r x 32k packed)
    u16* Bsh = (u16*)(SH + 98304);       // [3][2][4096]  (buf, kh, 128r x 32k packed)

    const int tid = threadIdx.x;
    const int lane = tid & 63, wid = tid >> 6;
    const int sk = wid & 1, ww = wid >> 1;     // K-half selector, pair id
    const int wm = ww >> 1, wn = ww & 1;       // pair tile position (2M x 2N)
    const int m0 = blockIdx.x * 256, n0 = blockIdx.y * 128;
    const int r = lane & 15, g = lane >> 4;

    f32x4 acc[8][4] = {};

    // ---- staging: linear LDS dest <- inverse-swizzled global source ----
    const int p0 = tid >> 3;              // phys row within 8KB round
    const int ci = tid & 7;               // 16B chunk within 128B phys row
    const int cl = ci ^ (p0 & 7);         // logical chunk
    const int trow = 2 * p0 + (cl >> 2);  // logical tile row
    const int colb = (cl & 3) * 8;        // logical col (bf16) within 32-col region
    const u16* aS = A + (long)(m0 + trow) * K + colb;
    const u16* bS = Bm + (long)(n0 + trow) * K + colb;
    const long rowskip = (long)128 * K;
    const int ldst = tid * 8;             // u16 offset within 8KB round

    auto STG_A = [&](int buf, int kh, int kq) {   // 2 gloads (rows 0-127, 128-255)
        const u16* sp = aS + kq * 32;
        u16* d = Ash + buf * 16384 + kh * 8192 + ldst;
        gload16(sp, d);
        gload16(sp + rowskip, d + 4096);
    };
    auto STG_B = [&](int buf, int kh, int kq) {   // 1 gload (rows 0-127)
        gload16(bS + kq * 32, Bsh + buf * 8192 + kh * 4096 + ldst);
    };

    // ---- fragment reads: byte = prow*128 + xa ----
    const int xa = (((((r & 1) << 2) | g) ^ (r >> 1)) << 4);
    const int arow0 = wm * 64 + (r >> 1);     // + mh*32 + m*8   (prow units)
    const int brow0 = wn * 32 + (r >> 1);     // + n*8
    auto RD = [&](const u16* base, int prow) -> bf16x8 {
        return *(const bf16x8*)((const char*)base + prow * 128 + xa);
    };

    bf16x8 bf_[4];   // B frags persist across the 2 m-half phases of a tile

#define PH(BUF, MH, STG, WAITV)                                                  \
    {                                                                            \
        bf16x8 af[4];                                                            \
        const u16* abase = Ash + (BUF) * 16384 + sk * 8192;                      \
        _Pragma("unroll")                                                        \
        for (int m = 0; m < 4; ++m)                                              \
            af[m] = RD(abase, arow0 + MH * 32 + m * 8);                          \
        if (MH == 0) {                                                           \
            const u16* bbase = Bsh + (BUF) * 8192 + sk * 4096;                   \
            _Pragma("unroll")                                                    \
            for (int n = 0; n < 4; ++n)                                          \
                bf_[n] = RD(bbase, brow0 + n * 8);                               \
        }                                                                        \
        STG;                                                                     \
        __builtin_amdgcn_s_barrier();                                            \
        asm volatile("s_waitcnt lgkmcnt(0)" ::: "memory");                       \
        __builtin_amdgcn_s_setprio(1);                                           \
        _Pragma("unroll")                                                        \
        for (int m = 0; m < 4; ++m)                                              \
            _Pragma("unroll")                                                    \
            for (int n = 0; n < 4; ++n)                                          \
                acc[MH * 4 + m][n] = __builtin_amdgcn_mfma_f32_16x16x32_bf16(    \
                    af[m], bf_[n], acc[MH * 4 + m][n], 0, 0, 0);                 \
        __builtin_amdgcn_s_setprio(0);                                           \
        WAITV;                                                                   \
        asm volatile("" ::: "memory");                                           \
        __builtin_amdgcn_s_barrier();                                            \
        asm volatile("" ::: "memory");                                           \
    }

    // prologue: stage tiles 0 and 1 (12 loads); retire tile-0's 6
    STG_A(0, 0, 0); STG_A(0, 1, 1); STG_B(0, 0, 0); STG_B(0, 1, 1);
    STG_A(1, 0, 2); STG_A(1, 1, 3); STG_B(1, 0, 2); STG_B(1, 1, 3);
    asm volatile("s_waitcnt vmcnt(6)" ::: "memory");
    __builtin_amdgcn_s_barrier();
    asm volatile("" ::: "memory");

    const int nt = K >> 6;                // 64-k tiles (K=1024 -> 16)
    for (int t = 0; t < nt; ++t) {
        const int cur = t % 3;
        const int nxt = (t + 2) % 3;
        const bool pf = (t + 2) < nt;
        const int kq = (t + 2) * 2;       // 32-k column index for staging
        if (pf) {
            PH(cur, 0, { STG_A(nxt, 0, kq); STG_B(nxt, 0, kq); }, )
            PH(cur, 1, { STG_A(nxt, 1, kq + 1); STG_B(nxt, 1, kq + 1); },
               asm volatile("s_waitcnt vmcnt(6)" ::: "memory");)
        } else {
            PH(cur, 0, , )
            PH(cur, 1, , asm volatile("s_waitcnt vmcnt(0)" ::: "memory");)
        }
    }
#undef PH

    // ---- pair K-half reduction via LDS (reuse staging memory) ----
    {
        f32x4* red = (f32x4*)SH;          // [4 pairs][32 idx][64 lanes] = 128 KiB
        if (sk == 1) {
#pragma unroll
            for (int i = 0; i < 32; ++i)
                red[ww * 2048 + i * 64 + lane] = acc[i >> 2][i & 3];
        }
        __syncthreads();
        if (sk == 0) {
#pragma unroll
            for (int i = 0; i < 32; ++i)
                acc[i >> 2][i & 3] += red[ww * 2048 + i * 64 + lane];
        }
    }
    if (sk != 0) return;                  // sk0 waves store (no barriers below)

    const long planeSz = (long)BZ * NH * TZ * HD;
    if constexpr (EPI == 0) {
        const int proj = n0 >> 10;                      // block-uniform (128 | 1024)
        u16* outp = (u16*)Cout;
        if (proj == 2) {
            // V transposed: [B][H][D][T]; regs are t-consecutive -> ushort4 stores
            const int bi = (m0 + wm * 128) >> 11;
#pragma unroll
            for (int n = 0; n < 4; ++n) {
                const int rr = (n0 & 1023) + wn * 64 + n * 16 + r;
                const int h = rr >> 6, d = rr & 63;
                const float bias = b2[rr];
                u16* vcol = outp + 2 * planeSz + (((long)bi * NH + h) * HD + d) * TZ;
#pragma unroll
                for (int mf = 0; mf < 8; ++mf) {
                    const int t0 = (m0 + wm * 128 + mf * 16 + g * 4) & 2047;
                    ushort4 o;
                    o.x = f2bf(acc[mf][n][0] + bias);
                    o.y = f2bf(acc[mf][n][1] + bias);
                    o.z = f2bf(acc[mf][n][2] + bias);
                    o.w = f2bf(acc[mf][n][3] + bias);
                    *(ushort4*)(vcol + t0) = o;
                }
            }
        } else {
#pragma unroll
            for (int n = 0; n < 4; ++n) {
                const int rr = (n0 & 1023) + wn * 64 + n * 16 + r;
                const int h = rr >> 6, d = rr & 63;
                float bias = (proj == 0 ? b0 : b1)[rr];
                if (proj == 0) bias *= QSCALE;
                const long pbase = (long)proj * planeSz + d;
#pragma unroll
                for (int mf = 0; mf < 8; ++mf)
#pragma unroll
                    for (int reg = 0; reg < 4; ++reg) {
                        const int row = m0 + wm * 128 + mf * 16 + g * 4 + reg;
                        const int bi = row >> 11, t = row & 2047;
                        outp[pbase + ((long)bi * NH + h) * (TZ * HD) + (long)t * HD] =
                            f2bf(acc[mf][n][reg] + bias);
                    }
            }
        }
    } else {
        float* outp = (float*)Cout;
#pragma unroll
        for (int n = 0; n < 4; ++n) {
            const int col = n0 + wn * 64 + n * 16 + r;
            const float bias = b0[col];
#pragma unroll
            for (int mf = 0; mf < 8; ++mf)
#pragma unroll
                for (int reg = 0; reg < 4; ++reg) {
                    const int row = m0 + wm * 128 + mf * 16 + g * 4 + reg;
                    outp[(long)row * N_EMBD + col] = acc[mf][n][reg] + bias;
                }
        }
    }
}

// ---------------- flash attention (causal, swapped-operand, in-register P) ----
// grid: 1024 blocks, 256 threads = 4 waves; wave owns 16 q-rows per item.
// Each block processes a BALANCED PAIR of 64-row q-blocks: (31-pr, pr) -> 33 k-tiles.
// bh->XCD swizzle: all 16 blocks of one bh land on one XCD (K/V L2 reuse).
__device__ __forceinline__ bf16x8 lds_swz8(const u16* base, int row, int colByte) {
    return *(const bf16x8*)((const char*)base + row * 128 + (colByte ^ ((row & 7) << 4)));
}

__global__ __launch_bounds__(256, 4) void attn_fwd(const u16* __restrict__ qkv, u16* __restrict__ yb) {
    const int i = blockIdx.x;
    const int xcd = i & 7, slot = i >> 3;
    const int bh = xcd + 8 * (slot & 7);     // 0..63, same-bh blocks share an XCD
    const int pr = slot >> 3;                // 0..15 pair id
    const int b = bh >> 4, h = bh & 15;
    const int tid = threadIdx.x, lane = tid & 63, w = tid >> 6;
    const int r = lane & 15, g = lane >> 4;

    __shared__ __align__(16) u16 Ksh[2][64 * 64];   // [k][d] swizzled
    __shared__ __align__(16) u16 Vsh[2][64 * 64];   // [d][k] swizzled

    const long planeSz = (long)BZ * NH * TZ * HD;
    const long bhoff = ((long)b * NH + h) * (long)TZ * HD;
    const u16* qp = qkv + bhoff;
    const u16* kp = qkv + planeSz + bhoff;
    const u16* vTp = qkv + 2 * planeSz + bhoff;      // [64][T]

    const int rr8 = tid >> 3, scb = tid & 7;  // staging coords

#pragma unroll 1
    for (int it = 0; it < 2; ++it) {
        const int qblk = it ? pr : (31 - pr);
        const int q0 = qblk * 64;
        const int nkt = qblk + 1;

        // hoist Q fragments (B-operand: lane r = q-col, g*8 = d-chunk)
        bf16x8 qf[2];
        {
            const int q = q0 + w * 16 + r;
#pragma unroll
            for (int ks = 0; ks < 2; ++ks)
                qf[ks] = *(const bf16x8*)(qp + (long)q * HD + ks * 32 + g * 8);
        }

        f32x4 yacc[4] = {};                    // y^T: [d-frag][q=r]
        float mrun = -__builtin_inff(), lpart = 0.f;

        // prologue stage tile 0
#pragma unroll
        for (int h2 = 0; h2 < 2; ++h2) {
            const int kk = h2 * 32 + rr8;
            const int ss = (scb ^ (kk & 7)) * 8;
            gload16(kp + (long)kk * HD + ss, &Ksh[0][h2 * 2048 + tid * 8]);
            gload16(vTp + (long)kk * TZ + ss, &Vsh[0][h2 * 2048 + tid * 8]);
        }

        auto tile = [&](int kt, auto maskc) {
            constexpr bool MASK = decltype(maskc)::value;
            const int cur = kt & 1;
            const int k0 = kt * 64;
            if (kt + 1 < nkt) {
                const int k0n = k0 + 64;
#pragma unroll
                for (int h2 = 0; h2 < 2; ++h2) {
                    const int kk = h2 * 32 + rr8;
                    const int ss = (scb ^ (kk & 7)) * 8;
                    gload16(kp + (long)(k0n + kk) * HD + ss, &Ksh[cur ^ 1][h2 * 2048 + tid * 8]);
                    gload16(vTp + (long)kk * TZ + k0n + ss, &Vsh[cur ^ 1][h2 * 2048 + tid * 8]);
                }
                asm volatile("s_waitcnt vmcnt(4)" ::: "memory");
            } else {
                asm volatile("s_waitcnt vmcnt(0)" ::: "memory");
            }
            __builtin_amdgcn_s_barrier();
            asm volatile("" ::: "memory");

            // S^T = K · Q^T  -> sac[nk]: row k, col q
            f32x4 sac[4] = {};
#pragma unroll
            for (int ks = 0; ks < 2; ++ks) {
                bf16x8 kf[4];
#pragma unroll
                for (int nk = 0; nk < 4; ++nk)
                    kf[nk] = lds_swz8(Ksh[cur], nk * 16 + r, ks * 64 + g * 16);
                __builtin_amdgcn_s_setprio(1);
#pragma unroll
                for (int nk = 0; nk < 4; ++nk)
                    sac[nk] = __builtin_amdgcn_mfma_f32_16x16x32_bf16(kf[nk], qf[ks], sac[nk], 0, 0, 0);
                __builtin_amdgcn_s_setprio(0);
            }

            // online softmax (log2 domain). lane owns 16 k of q-row r.
            if constexpr (MASK) {
                const int q = q0 + w * 16 + r;
#pragma unroll
                for (int nk = 0; nk < 4; ++nk)
#pragma unroll
                    for (int reg = 0; reg < 4; ++reg) {
                        const int k = k0 + nk * 16 + g * 4 + reg;
                        sac[nk][reg] = (k > q) ? -__builtin_inff() : sac[nk][reg];
                    }
            }
            float pmax;
            {
                float t0 = fmaxf(fmaxf(sac[0][0], sac[0][1]), fmaxf(sac[0][2], sac[0][3]));
                float t1 = fmaxf(fmaxf(sac[1][0], sac[1][1]), fmaxf(sac[1][2], sac[1][3]));
                float t2 = fmaxf(fmaxf(sac[2][0], sac[2][1]), fmaxf(sac[2][2], sac[2][3]));
                float t3 = fmaxf(fmaxf(sac[3][0], sac[3][1]), fmaxf(sac[3][2], sac[3][3]));
                pmax = fmaxf(fmaxf(t0, t1), fmaxf(t2, t3));
            }
            if (__any(pmax > mrun + 8.0f)) {
                float mx = pmax;
                mx = fmaxf(mx, __shfl_xor(mx, 16));
                mx = fmaxf(mx, __shfl_xor(mx, 32));
                const float mnew = fmaxf(mrun, mx);
                const float corr = __builtin_amdgcn_exp2f(mrun - mnew);
                lpart *= corr;
#pragma unroll
                for (int nd = 0; nd < 4; ++nd)
                    yacc[nd] *= corr;
                mrun = mnew;
            }
            float rs[4];
#pragma unroll
            for (int nk = 0; nk < 4; ++nk) {
                float p0 = __builtin_amdgcn_exp2f(sac[nk][0] - mrun);
                float p1 = __builtin_amdgcn_exp2f(sac[nk][1] - mrun);
                float p2 = __builtin_amdgcn_exp2f(sac[nk][2] - mrun);
                float p3 = __builtin_amdgcn_exp2f(sac[nk][3] - mrun);
                sac[nk][0] = p0; sac[nk][1] = p1;
                sac[nk][2] = p2; sac[nk][3] = p3;
                rs[nk] = (p0 + p1) + (p2 + p3);
            }
            lpart += (rs[0] + rs[1]) + (rs[2] + rs[3]);

            // pack P to bf16 + permlane exchange -> PV B-operand in-register
            u32 wv[4][2];
#pragma unroll
            for (int nk = 0; nk < 4; ++nk)
#pragma unroll
                for (int j2 = 0; j2 < 2; ++j2)
                    asm("v_cvt_pk_bf16_f32 %0, %1, %2"
                        : "=v"(wv[nk][j2])
                        : "v"(sac[nk][2 * j2]), "v"(sac[nk][2 * j2 + 1]));
            u32 pw[2][4];
#pragma unroll
            for (int ks = 0; ks < 2; ++ks) {
                u32 a0 = wv[2 * ks][0], b0 = wv[2 * ks + 1][0];
                u32 a1 = wv[2 * ks][1], b1 = wv[2 * ks + 1][1];
                asm("v_permlane32_swap_b32 %0, %1" : "+v"(a0), "+v"(b0));
                asm("v_permlane32_swap_b32 %0, %1" : "+v"(a1), "+v"(b1));
                asm("v_permlane16_swap_b32 %0, %1" : "+v"(a0), "+v"(b0));
                asm("v_permlane16_swap_b32 %0, %1" : "+v"(a1), "+v"(b1));
                pw[ks][0] = a0; pw[ks][1] = a1;
                pw[ks][2] = b0; pw[ks][3] = b1;
            }

            // y^T += V^T · P^T
#pragma unroll
            for (int ks = 0; ks < 2; ++ks) {
                bf16x8 vf[4];
#pragma unroll
                for (int nd = 0; nd < 4; ++nd)
                    vf[nd] = lds_swz8(Vsh[cur], nd * 16 + r, ks * 64 + g * 16);
                const u32x4 pwv = { pw[ks][0], pw[ks][1], pw[ks][2], pw[ks][3] };
                const bf16x8 pb = __builtin_bit_cast(bf16x8, pwv);
                __builtin_amdgcn_s_setprio(1);
#pragma unroll
                for (int nd = 0; nd < 4; ++nd)
                    yacc[nd] = __builtin_amdgcn_mfma_f32_16x16x32_bf16(vf[nd], pb, yacc[nd], 0, 0, 0);
                __builtin_amdgcn_s_setprio(0);
            }

            asm volatile("" ::: "memory");
            __builtin_amdgcn_s_barrier();
            asm volatile("" ::: "memory");
        };

        for (int kt = 0; kt < nkt - 1; ++kt) tile(kt, BoolC<false>{});
        tile(nkt - 1, BoolC<true>{});

        // epilogue: reduce l across g-lanes, y = y^T / l
        {
            float l = lpart;
            l += __shfl_xor(l, 16);
            l += __shfl_xor(l, 32);
            const float inv = 1.f / l;
            const int q = q0 + w * 16 + r;
            u16* orow = yb + ((long)b * TZ + q) * N_EMBD + h * HD;
#pragma unroll
            for (int nd = 0; nd < 4; ++nd) {
                ushort4 o;
                o.x = f2bf(yacc[nd][0] * inv);
                o.y = f2bf(yacc[nd][1] * inv);
                o.z = f2bf(yacc[nd][2] * inv);
                o.w = f2bf(yacc[nd][3] * inv);
                *(ushort4*)(orow + nd * 16 + g * 4) = o;
            }
        }
    }
}

extern "C" void kernel_launch(void* const* d_in, const int* in_sizes, int n_in,
                              void* d_out, int out_size, void* d_ws, size_t ws_size,
                              hipStream_t stream) {
    const float* x  = (const float*)d_in[0];
    const float* Wq = (const float*)d_in[1];
    const float* bq = (const float*)d_in[2];
    const float* Wk = (const float*)d_in[3];
    const float* bk = (const float*)d_in[4];
    const float* Wv = (const float*)d_in[5];
    const float* bv = (const float*)d_in[6];
    const float* Wc = (const float*)d_in[7];
    const float* bc = (const float*)d_in[8];

    char* ws = (char*)d_ws;
    u16* xb   = (u16*)(ws);                  // 8192x1024 bf16   (16 MB)
    u16* wqkv = (u16*)(ws + 16777216);       // 3072x1024 bf16   (6 MB)
    u16* wcb  = (u16*)(ws + 23068672);       // 1024x1024 bf16   (2 MB)
    u16* qkv  = (u16*)(ws + 25165824);       // Q,K,[V^T] planes (48 MB)
    u16* yb   = (u16*)(ws + 75497472);       // 8192x1024 bf16   (16 MB)

    // converts (Wq pre-scaled by QSCALE so S arrives in log2 domain)
    cvt_f32_bf16<<<8192, 256, 0, stream>>>(x, xb, 2097152, 1.0f);
    cvt_f32_bf16<<<1024, 256, 0, stream>>>(Wq, wqkv, 262144, QSCALE);
    cvt_f32_bf16<<<1024, 256, 0, stream>>>(Wk, wqkv + 1048576, 262144, 1.0f);
    cvt_f32_bf16<<<1024, 256, 0, stream>>>(Wv, wqkv + 2097152, 262144, 1.0f);
    cvt_f32_bf16<<<1024, 256, 0, stream>>>(Wc, wcb, 262144, 1.0f);

    // qkv projection: [8192,1024] x [3072,1024]^T -> qkv scatter (V transposed)
    // grid 32x24 = 768 = 3*256 blocks: perfect CU packing
    gemm_bt<0><<<dim3(32, 24), 512, 0, stream>>>(xb, wqkv, bq, bk, bv, (void*)qkv, 1024);

    // causal attention (balanced paired q-blocks, XCD-swizzled bh)
    attn_fwd<<<1024, 256, 0, stream>>>(qkv, yb);

    // output projection: [8192,1024] x [1024,1024]^T + bc -> fp32 out
    // grid 32x8 = 256 blocks: exactly one per CU
    gemm_bt<1><<<dim3(32, 8), 512, 0, stream>>>(yb, wcb, bc, nullptr, nullptr, d_out, 1024);
}

// Round 4
// 161.460 us; speedup vs baseline: 2.7132x; 2.7132x over previous
//
#include <hip/hip_runtime.h>
#include <hip/hip_bf16.h>

typedef __bf16 bf16x8 __attribute__((ext_vector_type(8)));
typedef float f32x4 __attribute__((ext_vector_type(4)));
typedef unsigned short u16;
typedef u16 u16x8 __attribute__((ext_vector_type(8)));
typedef unsigned int u32;
typedef u32 u32x4 __attribute__((ext_vector_type(4)));

#define N_EMBD 1024
#define NH 16
#define HD 64
#define BZ 4
#define TZ 2048
#define QSCALE 0.18033688011f   // 1/sqrt(64) * log2(e)

template<bool B> struct BoolC { static constexpr bool value = B; };

__device__ __forceinline__ u16 f2bf(float f) {
    return __builtin_bit_cast(u16, (__bf16)f);
}

__device__ __forceinline__ void gload16(const void* g, void* l) {
    __builtin_amdgcn_global_load_lds(
        (const __attribute__((address_space(1))) void*)g,
        (__attribute__((address_space(3))) void*)l, 16, 0, 0);
}

// ---------------- fused fp32 -> bf16 converts (x + 4 weights) --------------
// blocks 0..8191: x; 8192..9215: Wq (xQSCALE); 9216..10239: Wk;
// 10240..11263: Wv; 11264..12287: Wc.  All segments exact-sized (no bounds chk).
__global__ void cvt_all(const float* __restrict__ x,  const float* __restrict__ Wq,
                        const float* __restrict__ Wk, const float* __restrict__ Wv,
                        const float* __restrict__ Wc, u16* __restrict__ xb,
                        u16* __restrict__ wqkv, u16* __restrict__ wcb) {
    const int blk = blockIdx.x;
    const float* src; u16* dst; int base; float scale = 1.0f;
    if (blk < 8192)       { src = x;  dst = xb;             base = blk; }
    else if (blk < 9216)  { src = Wq; dst = wqkv;           base = blk - 8192; scale = QSCALE; }
    else if (blk < 10240) { src = Wk; dst = wqkv + 1048576; base = blk - 9216; }
    else if (blk < 11264) { src = Wv; dst = wqkv + 2097152; base = blk - 10240; }
    else                  { src = Wc; dst = wcb;            base = blk - 11264; }
    const int i = base * 256 + threadIdx.x;
    float4 f = ((const float4*)src)[i];
    ushort4 o;
    o.x = f2bf(f.x * scale); o.y = f2bf(f.y * scale);
    o.z = f2bf(f.z * scale); o.w = f2bf(f.w * scale);
    ((ushort4*)dst)[i] = o;
}

// ---------------- bf16 GEMM, C = A * B^T + bias ----------------------------
// 256x128 tile, 8 waves (4M x 2N), 512 threads. K split into 32-wide phases.
// 6-region rotating LDS pipeline (144 KiB), ONE barrier per phase:
//   phase p: barrier; ds_read frags(p+1) [reg-dbuf, counted lgkm by compiler];
//            stage region for phase p+5 (3 x global_load_lds); MFMA frags(p);
//            vmcnt(9)  [retires region p+2's staging -> resident for p+1's reads]
// WAR: stage target (p+5)%6 == (p-1)%6, whose reads completed before this barrier.
// Row-pair-packed 128B phys rows, XOR swizzle -> conflict-free ds_read_b128.
// EPI=0: scatter to qkv: Q,K planes [B][H][T][64]; V plane TRANSPOSED [B][H][64][T]
//        (Q plane pre-scaled by QSCALE via Wq/bq scaling)
// EPI=1: plain fp32 [M,1024] with bias b0
template<int EPI>
__global__ __launch_bounds__(512, 2) void gemm_bt(
    const u16* __restrict__ A, const u16* __restrict__ Bm,
    const float* __restrict__ b0, const float* __restrict__ b1, const float* __restrict__ b2,
    void* __restrict__ Cout, int K) {
    __shared__ __align__(16) u16 Ash[6 * 8192];   // 6 x (256 rows x 32 k) = 96 KB
    __shared__ __align__(16) u16 Bsh[6 * 4096];   // 6 x (128 rows x 32 k) = 48 KB

    const int tid = threadIdx.x;
    const int lane = tid & 63, wid = tid >> 6;
    const int wm = wid >> 1, wn = wid & 1;        // 4M x 2N wave grid
    const int m0 = blockIdx.x * 256, n0 = blockIdx.y * 128;
    const int r = lane & 15, g = lane >> 4;

    f32x4 acc[4][4] = {};

    // ---- staging: linear LDS dest <- inverse-swizzled global source ----
    const int p0 = tid >> 3;              // phys row within 8KB round
    const int ci = tid & 7;               // 16B chunk within 128B phys row
    const int cl = ci ^ (p0 & 7);         // logical chunk
    const int trow = 2 * p0 + (cl >> 2);  // logical tile row
    const int colb = (cl & 3) * 8;        // logical col (bf16) within 32-col region
    const u16* aS = A + (long)(m0 + trow) * K + colb;
    const u16* bS = Bm + (long)(n0 + trow) * K + colb;
    const long rowskip = (long)128 * K;
    const int ldst = tid * 8;             // u16 offset within 8KB round

    auto STAGE = [&](int sig, int kq) {   // 3 loads: A(2 rounds) + B(1)
        const u16* spA = aS + kq * 32;
        gload16(spA, &Ash[sig * 8192 + ldst]);
        gload16(spA + rowskip, &Ash[sig * 8192 + 4096 + ldst]);
        gload16(bS + kq * 32, &Bsh[sig * 4096 + ldst]);
    };

    // ---- fragment reads: byte = prow*128 + xa ----
    const int xa = (((((r & 1) << 2) | g) ^ (r >> 1)) << 4);
    const int arow0 = wm * 32 + (r >> 1);
    const int brow0 = wn * 32 + (r >> 1);
    auto RD = [&](const u16* base, int prow) -> bf16x8 {
        return *(const bf16x8*)((const char*)base + prow * 128 + xa);
    };

    bf16x8 fa0[4], fb0[4], fa1[4], fb1[4];   // double-buffered fragment sets

    auto READF = [&](int rho, bf16x8* fa, bf16x8* fb) {
#pragma unroll
        for (int m = 0; m < 4; ++m) fa[m] = RD(&Ash[rho * 8192], arow0 + m * 8);
#pragma unroll
        for (int n = 0; n < 4; ++n) fb[n] = RD(&Bsh[rho * 4096], brow0 + n * 8);
    };
    auto MM = [&](bf16x8* fa, bf16x8* fb) {
        __builtin_amdgcn_s_setprio(1);
#pragma unroll
        for (int m = 0; m < 4; ++m)
#pragma unroll
            for (int n = 0; n < 4; ++n)
                acc[m][n] = __builtin_amdgcn_mfma_f32_16x16x32_bf16(fa[m], fb[n], acc[m][n], 0, 0, 0);
        __builtin_amdgcn_s_setprio(0);
    };
    auto BAR = [&] {
        asm volatile("" ::: "memory");
        __builtin_amdgcn_s_barrier();
        asm volatile("" ::: "memory");
    };

    const int nph = K >> 5;               // 32-wide k phases (K=1024 -> 32)

    // prologue: stage regions 0..4, retire 0..1, read frags(0)
    STAGE(0, 0); STAGE(1, 1); STAGE(2, 2); STAGE(3, 3); STAGE(4, 4);
    asm volatile("s_waitcnt vmcnt(9)" ::: "memory");
    BAR();
    READF(0, fa0, fb0);

    int rho = 0;
    for (int p = 0; p + 2 < nph; p += 2) {
        const int rho1 = rho + 1;
        const int rho2 = (rho + 2 == 6) ? 0 : rho + 2;
        const int sigE = (rho == 0) ? 5 : rho - 1;
        const int kqE = (p + 5 < nph) ? p + 5 : 0;   // clamped tail -> dead region
        const int kqO = (p + 6 < nph) ? p + 6 : 0;
        // even phase p: consume rho
        BAR();
        READF(rho1, fa1, fb1);
        STAGE(sigE, kqE);
        MM(fa0, fb0);
        asm volatile("s_waitcnt vmcnt(9)" ::: "memory");
        // odd phase p+1: consume rho1
        BAR();
        READF(rho2, fa0, fb0);
        STAGE(rho, kqO);
        MM(fa1, fb1);
        asm volatile("s_waitcnt vmcnt(9)" ::: "memory");
        rho = rho2;
    }
    // phase nph-2: consume rho; read last frags; clamped stage keeps vmcnt flow
    {
        const int rho1 = rho + 1;
        const int sigE = (rho == 0) ? 5 : rho - 1;
        BAR();
        READF(rho1, fa1, fb1);
        STAGE(sigE, 0);
        MM(fa0, fb0);
        asm volatile("s_waitcnt vmcnt(9)" ::: "memory");
    }
    // phase nph-1: consume rho+1; no reads, no stage
    MM(fa1, fb1);
    asm volatile("s_waitcnt vmcnt(0)" ::: "memory");   // drain clamped prefetches

    const long planeSz = (long)BZ * NH * TZ * HD;
    if constexpr (EPI == 0) {
        const int proj = n0 >> 10;                      // block-uniform (128 | 1024)
        u16* outp = (u16*)Cout;
        if (proj == 2) {
            // V transposed: [B][H][D][T]; regs are t-consecutive -> ushort4 stores
            const int bi = (m0 + wm * 64) >> 11;
#pragma unroll
            for (int n = 0; n < 4; ++n) {
                const int rr = (n0 & 1023) + wn * 64 + n * 16 + r;
                const int h = rr >> 6, d = rr & 63;
                const float bias = b2[rr];
                u16* vcol = outp + 2 * planeSz + (((long)bi * NH + h) * HD + d) * TZ;
#pragma unroll
                for (int m = 0; m < 4; ++m) {
                    const int t0 = (m0 + wm * 64 + m * 16 + g * 4) & 2047;
                    ushort4 o;
                    o.x = f2bf(acc[m][n][0] + bias);
                    o.y = f2bf(acc[m][n][1] + bias);
                    o.z = f2bf(acc[m][n][2] + bias);
                    o.w = f2bf(acc[m][n][3] + bias);
                    *(ushort4*)(vcol + t0) = o;
                }
            }
        } else {
#pragma unroll
            for (int n = 0; n < 4; ++n) {
                const int rr = (n0 & 1023) + wn * 64 + n * 16 + r;
                const int h = rr >> 6, d = rr & 63;
                float bias = (proj == 0 ? b0 : b1)[rr];
                if (proj == 0) bias *= QSCALE;
                const long pbase = (long)proj * planeSz + d;
#pragma unroll
                for (int m = 0; m < 4; ++m)
#pragma unroll
                    for (int reg = 0; reg < 4; ++reg) {
                        const int row = m0 + wm * 64 + m * 16 + g * 4 + reg;
                        const int bi = row >> 11, t = row & 2047;
                        outp[pbase + ((long)bi * NH + h) * (TZ * HD) + (long)t * HD] =
                            f2bf(acc[m][n][reg] + bias);
                    }
            }
        }
    } else {
        float* outp = (float*)Cout;
#pragma unroll
        for (int n = 0; n < 4; ++n) {
            const int col = n0 + wn * 64 + n * 16 + r;
            const float bias = b0[col];
#pragma unroll
            for (int m = 0; m < 4; ++m)
#pragma unroll
                for (int reg = 0; reg < 4; ++reg) {
                    const int row = m0 + wm * 64 + m * 16 + g * 4 + reg;
                    outp[(long)row * N_EMBD + col] = acc[m][n][reg] + bias;
                }
        }
    }
}

// ---------------- flash attention (causal, swapped-operand, in-register P) ----
// grid: 512 blocks, 512 threads = 8 waves; wave owns 16 q-rows.
// Block processes a BALANCED PAIR of 128-row q-blocks: (15-pr, pr) -> 36 k-tiles.
// K/V tile staged ONCE per block amortizes over 8 waves (halves DMA bytes vs
// 4-wave blocks). Last TWO tiles masked (128-row block spans 2 diagonal k-tiles).
// bh->XCD swizzle: all 8 blocks of one bh land on one XCD (K/V L2 reuse).
__device__ __forceinline__ bf16x8 lds_swz8(const u16* base, int row, int colByte) {
    return *(const bf16x8*)((const char*)base + row * 128 + (colByte ^ ((row & 7) << 4)));
}

__global__ __launch_bounds__(512, 2) void attn_fwd(const u16* __restrict__ qkv, u16* __restrict__ yb) {
    const int i = blockIdx.x;
    const int xcd = i & 7, slot = i >> 3;
    const int bh = xcd + 8 * (slot & 7);     // 0..63, same-bh blocks share an XCD
    const int pr = slot >> 3;                // 0..7 pair id
    const int b = bh >> 4, h = bh & 15;
    const int tid = threadIdx.x, lane = tid & 63, w = tid >> 6;   // w 0..7
    const int r = lane & 15, g = lane >> 4;

    __shared__ __align__(16) u16 Ksh[2][64 * 64];   // [k][d] swizzled
    __shared__ __align__(16) u16 Vsh[2][64 * 64];   // [d][k] swizzled

    const long planeSz = (long)BZ * NH * TZ * HD;
    const long bhoff = ((long)b * NH + h) * (long)TZ * HD;
    const u16* qp = qkv + bhoff;
    const u16* kp = qkv + planeSz + bhoff;
    const u16* vTp = qkv + 2 * planeSz + bhoff;      // [64][T]

    // staging coords: 512 threads cover a full 64x64 bf16 tile in ONE gload
    const int rr8 = tid >> 3;                 // tile row 0..63
    const int ss = ((tid & 7) ^ (rr8 & 7)) * 8;   // pre-swizzled source chunk

#pragma unroll 1
    for (int it = 0; it < 2; ++it) {
        const int qblk = it ? pr : (15 - pr);
        const int q0 = qblk * 128;
        const int nkt = 2 * qblk + 2;

        // hoist Q fragments (B-operand: lane r = q-col, g*8 = d-chunk)
        bf16x8 qf[2];
        {
            const int q = q0 + w * 16 + r;
#pragma unroll
            for (int ks = 0; ks < 2; ++ks)
                qf[ks] = *(const bf16x8*)(qp + (long)q * HD + ks * 32 + g * 8);
        }

        f32x4 yacc[4] = {};                    // y^T: [d-frag][q=r]
        float mrun = -__builtin_inff(), lpart = 0.f;

        // prologue stage tile 0 (K: 8KB, V: 8KB -> 2 gloads)
        gload16(kp + (long)rr8 * HD + ss, &Ksh[0][tid * 8]);
        gload16(vTp + (long)rr8 * TZ + ss, &Vsh[0][tid * 8]);

        auto tile = [&](int kt, auto maskc) {
            constexpr bool MASK = decltype(maskc)::value;
            const int cur = kt & 1;
            const int k0 = kt * 64;
            if (kt + 1 < nkt) {
                const int k0n = k0 + 64;
                gload16(kp + (long)(k0n + rr8) * HD + ss, &Ksh[cur ^ 1][tid * 8]);
                gload16(vTp + (long)rr8 * TZ + k0n + ss, &Vsh[cur ^ 1][tid * 8]);
                asm volatile("s_waitcnt vmcnt(2)" ::: "memory");
            } else {
                asm volatile("s_waitcnt vmcnt(0)" ::: "memory");
            }
            __builtin_amdgcn_s_barrier();
            asm volatile("" ::: "memory");

            // S^T = K · Q^T  -> sac[nk]: row k, col q
            f32x4 sac[4] = {};
#pragma unroll
            for (int ks = 0; ks < 2; ++ks) {
                bf16x8 kf[4];
#pragma unroll
                for (int nk = 0; nk < 4; ++nk)
                    kf[nk] = lds_swz8(Ksh[cur], nk * 16 + r, ks * 64 + g * 16);
                __builtin_amdgcn_s_setprio(1);
#pragma unroll
                for (int nk = 0; nk < 4; ++nk)
                    sac[nk] = __builtin_amdgcn_mfma_f32_16x16x32_bf16(kf[nk], qf[ks], sac[nk], 0, 0, 0);
                __builtin_amdgcn_s_setprio(0);
            }

            // online softmax (log2 domain). lane owns 16 k of q-row r.
            if constexpr (MASK) {
                const int q = q0 + w * 16 + r;
#pragma unroll
                for (int nk = 0; nk < 4; ++nk)
#pragma unroll
                    for (int reg = 0; reg < 4; ++reg) {
                        const int k = k0 + nk * 16 + g * 4 + reg;
                        sac[nk][reg] = (k > q) ? -__builtin_inff() : sac[nk][reg];
                    }
            }
            float pmax;
            {
                float t0 = fmaxf(fmaxf(sac[0][0], sac[0][1]), fmaxf(sac[0][2], sac[0][3]));
                float t1 = fmaxf(fmaxf(sac[1][0], sac[1][1]), fmaxf(sac[1][2], sac[1][3]));
                float t2 = fmaxf(fmaxf(sac[2][0], sac[2][1]), fmaxf(sac[2][2], sac[2][3]));
                float t3 = fmaxf(fmaxf(sac[3][0], sac[3][1]), fmaxf(sac[3][2], sac[3][3]));
                pmax = fmaxf(fmaxf(t0, t1), fmaxf(t2, t3));
            }
            if (__any(pmax > mrun + 8.0f)) {
                float mx = pmax;
                mx = fmaxf(mx, __shfl_xor(mx, 16));
                mx = fmaxf(mx, __shfl_xor(mx, 32));
                const float mnew = fmaxf(mrun, mx);
                const float corr = __builtin_amdgcn_exp2f(mrun - mnew);
                lpart *= corr;
#pragma unroll
                for (int nd = 0; nd < 4; ++nd)
                    yacc[nd] *= corr;
                mrun = mnew;
            }
            float rs[4];
#pragma unroll
            for (int nk = 0; nk < 4; ++nk) {
                float p0 = __builtin_amdgcn_exp2f(sac[nk][0] - mrun);
                float p1 = __builtin_amdgcn_exp2f(sac[nk][1] - mrun);
                float p2 = __builtin_amdgcn_exp2f(sac[nk][2] - mrun);
                float p3 = __builtin_amdgcn_exp2f(sac[nk][3] - mrun);
                sac[nk][0] = p0; sac[nk][1] = p1;
                sac[nk][2] = p2; sac[nk][3] = p3;
                rs[nk] = (p0 + p1) + (p2 + p3);
            }
            lpart += (rs[0] + rs[1]) + (rs[2] + rs[3]);

            // pack P to bf16 + permlane exchange -> PV B-operand in-register
            u32 wv[4][2];
#pragma unroll
            for (int nk = 0; nk < 4; ++nk)
#pragma unroll
                for (int j2 = 0; j2 < 2; ++j2)
                    asm("v_cvt_pk_bf16_f32 %0, %1, %2"
                        : "=v"(wv[nk][j2])
                        : "v"(sac[nk][2 * j2]), "v"(sac[nk][2 * j2 + 1]));
            u32 pw[2][4];
#pragma unroll
            for (int ks = 0; ks < 2; ++ks) {
                u32 a0 = wv[2 * ks][0], b0 = wv[2 * ks + 1][0];
                u32 a1 = wv[2 * ks][1], b1 = wv[2 * ks + 1][1];
                asm("v_permlane32_swap_b32 %0, %1" : "+v"(a0), "+v"(b0));
                asm("v_permlane32_swap_b32 %0, %1" : "+v"(a1), "+v"(b1));
                asm("v_permlane16_swap_b32 %0, %1" : "+v"(a0), "+v"(b0));
                asm("v_permlane16_swap_b32 %0, %1" : "+v"(a1), "+v"(b1));
                pw[ks][0] = a0; pw[ks][1] = a1;
                pw[ks][2] = b0; pw[ks][3] = b1;
            }

            // y^T += V^T · P^T
#pragma unroll
            for (int ks = 0; ks < 2; ++ks) {
                bf16x8 vf[4];
#pragma unroll
                for (int nd = 0; nd < 4; ++nd)
                    vf[nd] = lds_swz8(Vsh[cur], nd * 16 + r, ks * 64 + g * 16);
                const u32x4 pwv = { pw[ks][0], pw[ks][1], pw[ks][2], pw[ks][3] };
                const bf16x8 pb = __builtin_bit_cast(bf16x8, pwv);
                __builtin_amdgcn_s_setprio(1);
#pragma unroll
                for (int nd = 0; nd < 4; ++nd)
                    yacc[nd] = __builtin_amdgcn_mfma_f32_16x16x32_bf16(vf[nd], pb, yacc[nd], 0, 0, 0);
                __builtin_amdgcn_s_setprio(0);
            }

            asm volatile("" ::: "memory");
            __builtin_amdgcn_s_barrier();
            asm volatile("" ::: "memory");
        };

        for (int kt = 0; kt + 2 < nkt; ++kt) tile(kt, BoolC<false>{});
        tile(nkt - 2, BoolC<true>{});     // 128-row q-block spans TWO diagonal tiles
        tile(nkt - 1, BoolC<true>{});

        // epilogue: reduce l across g-lanes, y = y^T / l
        {
            float l = lpart;
            l += __shfl_xor(l, 16);
            l += __shfl_xor(l, 32);
            const float inv = 1.f / l;
            const int q = q0 + w * 16 + r;
            u16* orow = yb + ((long)b * TZ + q) * N_EMBD + h * HD;
#pragma unroll
            for (int nd = 0; nd < 4; ++nd) {
                ushort4 o;
                o.x = f2bf(yacc[nd][0] * inv);
                o.y = f2bf(yacc[nd][1] * inv);
                o.z = f2bf(yacc[nd][2] * inv);
                o.w = f2bf(yacc[nd][3] * inv);
                *(ushort4*)(orow + nd * 16 + g * 4) = o;
            }
        }
    }
}

extern "C" void kernel_launch(void* const* d_in, const int* in_sizes, int n_in,
                              void* d_out, int out_size, void* d_ws, size_t ws_size,
                              hipStream_t stream) {
    const float* x  = (const float*)d_in[0];
    const float* Wq = (const float*)d_in[1];
    const float* bq = (const float*)d_in[2];
    const float* Wk = (const float*)d_in[3];
    const float* bk = (const float*)d_in[4];
    const float* Wv = (const float*)d_in[5];
    const float* bv = (const float*)d_in[6];
    const float* Wc = (const float*)d_in[7];
    const float* bc = (const float*)d_in[8];

    char* ws = (char*)d_ws;
    u16* xb   = (u16*)(ws);                  // 8192x1024 bf16   (16 MB)
    u16* wqkv = (u16*)(ws + 16777216);       // 3072x1024 bf16   (6 MB)
    u16* wcb  = (u16*)(ws + 23068672);       // 1024x1024 bf16   (2 MB)
    u16* qkv  = (u16*)(ws + 25165824);       // Q,K,[V^T] planes (48 MB)
    u16* yb   = (u16*)(ws + 75497472);       // 8192x1024 bf16   (16 MB)

    // fused converts (Wq pre-scaled by QSCALE so S arrives in log2 domain)
    cvt_all<<<12288, 256, 0, stream>>>(x, Wq, Wk, Wv, Wc, xb, wqkv, wcb);

    // qkv projection: [8192,1024] x [3072,1024]^T -> qkv scatter (V transposed)
    // grid 32x24 = 768 = 3*256 blocks: perfect CU packing
    gemm_bt<0><<<dim3(32, 24), 512, 0, stream>>>(xb, wqkv, bq, bk, bv, (void*)qkv, 1024);

    // causal attention (128-row paired q-blocks, 8-wave blocks, XCD-swizzled bh)
    attn_fwd<<<512, 512, 0, stream>>>(qkv, yb);

    // output projection: [8192,1024] x [1024,1024]^T + bc -> fp32 out
    // grid 32x8 = 256 blocks: exactly one per CU
    gemm_bt<1><<<dim3(32, 8), 512, 0, stream>>>(yb, wcb, bc, nullptr, nullptr, d_out, 1024);
}